// Round 3
// baseline (694.889 us; speedup 1.0000x reference)
//
#include <hip/hip_runtime.h>

// Problem constants
#define PAD_ID 0
#define NTOK   16384          // B*L = 16*1024
#define DIM    768
#define KLAT   5000
#define KPAD   5024           // 157*32, zero-padded latent rows
#define NSTEP  157            // 5024/32
#define TILE_SH 24576         // shorts per 32x768 tile (48 KB)

typedef float f32x4  __attribute__((ext_vector_type(4)));
typedef float f32x16 __attribute__((ext_vector_type(16)));
typedef __bf16 bf16x8 __attribute__((ext_vector_type(8)));

__device__ __forceinline__ unsigned short f2bf(float f) {
    unsigned int u = __float_as_uint(f);
    u += 0x7fffu + ((u >> 16) & 1u);   // RNE
    return (unsigned short)(u >> 16);
}
__device__ __forceinline__ float bf2f(unsigned short h) {
    return __uint_as_float(((unsigned int)h) << 16);
}
__device__ __forceinline__ float fast_tanh(float x) {
    // 1 - 2/(e^{2x}+1); graceful at +-inf. Error << bf16 ulp.
    return 1.0f - 2.0f / (__expf(2.0f * x) + 1.0f);
}
__device__ __forceinline__ void async_cp16(const unsigned short* g, unsigned short* l) {
    __builtin_amdgcn_global_load_lds(
        (const __attribute__((address_space(1))) unsigned int*)g,
        (__attribute__((address_space(3))) unsigned int*)l, 16, 0, 0);
}

// ---------------------------------------------------------------------------
// Kernel 0: latent -> latbS (32x32x16 A-frag order) and latbT (d-major), bf16.
//   latbS[t][kf16][lane][j] = Lat[t*32 + (lane&31)][kf16*16 + (lane>>5)*8 + j]
//     (kf16 = 0..47)  -> S-phase ds_read_b128 frag-linear, conflict-free.
//   latbT[t][d][kk]   = Lat[t*32 + kk][d]  -> O-phase coalesced global dwordx4.
// Both have exactly NSTEP*48*64 == NSTEP*768*4 8-short groups: one kernel.
// ---------------------------------------------------------------------------
__global__ __launch_bounds__(256) void cvt_lat(const float* __restrict__ latent,
                                               unsigned short* __restrict__ latbS,
                                               unsigned short* __restrict__ latbT) {
    int g = blockIdx.x * 256 + threadIdx.x;
    if (g >= NSTEP * 48 * 64) return;
    // ---- S part ----
    {
        int lane = g & 63; int rest = g >> 6;
        int kf = rest % 48; int t = rest / 48;
        int row = t * 32 + (lane & 31);
        int col = kf * 16 + (lane >> 5) * 8;
        float4 v0 = make_float4(0.f,0.f,0.f,0.f), v1 = v0;
        if (row < KLAT) {
            v0 = *(const float4*)(latent + (long)row * DIM + col);
            v1 = *(const float4*)(latent + (long)row * DIM + col + 4);
        }
        uint4 o;
        o.x = (unsigned)f2bf(v0.x) | ((unsigned)f2bf(v0.y) << 16);
        o.y = (unsigned)f2bf(v0.z) | ((unsigned)f2bf(v0.w) << 16);
        o.z = (unsigned)f2bf(v1.x) | ((unsigned)f2bf(v1.y) << 16);
        o.w = (unsigned)f2bf(v1.z) | ((unsigned)f2bf(v1.w) << 16);
        *(uint4*)(latbS + (size_t)g * 8) = o;
    }
    // ---- T part ----
    {
        int kk8 = g & 3; int rest = g >> 2;
        int d = rest % DIM; int t = rest / DIM;
        unsigned short v[8];
        #pragma unroll
        for (int j = 0; j < 8; ++j) {
            int row = t * 32 + kk8 * 8 + j;
            v[j] = (row < KLAT) ? f2bf(latent[(long)row * DIM + d]) : (unsigned short)0;
        }
        *(uint4*)(latbT + (size_t)g * 8) = *(uint4*)v;
    }
}

// ---------------------------------------------------------------------------
// Kernel 1: lang_emb = tanh(masked-mean of char embeddings), stored bf16.
// ---------------------------------------------------------------------------
__global__ __launch_bounds__(192) void build_lang(const int* __restrict__ x,
                                                  const float* __restrict__ cemb,
                                                  unsigned short* __restrict__ langb) {
    int tok = blockIdx.x;
    int t = threadIdx.x;
    const int* xs = x + tok * 8;
    int ids[8]; int cnt = 0;
    #pragma unroll
    for (int c = 0; c < 8; ++c) { ids[c] = xs[c]; cnt += (ids[c] != PAD_ID); }
    float4 acc = make_float4(0.f, 0.f, 0.f, 0.f);
    #pragma unroll
    for (int c = 0; c < 8; ++c) {
        if (ids[c] != PAD_ID) {
            float4 v = *(const float4*)(cemb + (long)ids[c] * DIM + t * 4);
            acc.x += v.x; acc.y += v.y; acc.z += v.z; acc.w += v.w;
        }
    }
    float rc = 1.0f / (float)max(cnt, 1);
    unsigned int u0 = (unsigned int)f2bf(fast_tanh(acc.x * rc)) |
                      ((unsigned int)f2bf(fast_tanh(acc.y * rc)) << 16);
    unsigned int u1 = (unsigned int)f2bf(fast_tanh(acc.z * rc)) |
                      ((unsigned int)f2bf(fast_tanh(acc.w * rc)) << 16);
    *(uint2*)(langb + tok * DIM + t * 4) = make_uint2(u0, u1);
}

// ---------------------------------------------------------------------------
// Kernel 2: fused S^T -> exp -> P@Lat -> /l + lang + special override.
// 256 blocks x 64 tokens, 4 waves. Wave (h = w&1, t = w>>1):
//   S-phase: one 32x32 tile (32 lats x tokens t*32..t*32+32) over K-half h
//     via mfma_32x32x16 (A = latent frag from LDS, B = Q frags in regs;
//     24 A-reads + 24 MFMAs per step), then 2-way partial exchange across
//     the wave pair through sX (2 b128 writes + 2 reads + 8 adds).
//   exp on the 8 owned f32 -> sP (stride-44, conflict-free b64 writes).
//   O-phase: unchanged 16x16x32, wave owns D-slice 192, bO direct-global.
// DMA of tile s+1 issues right after the post-S barrier (widest window).
// ---------------------------------------------------------------------------
__global__ __launch_bounds__(256, 1) void fused_sde(
        const int* __restrict__ x, const float* __restrict__ cemb,
        const unsigned short* __restrict__ langb,
        const unsigned short* __restrict__ latbS,
        const unsigned short* __restrict__ latbT,
        float* __restrict__ out) {
    __shared__ unsigned short sLat[TILE_SH];   // 48 KB frag-linear latent tile
    __shared__ float4 sX[2][4][64];            // 8 KB partial-exchange
    __shared__ unsigned short sP[64 * 44];     // 5.5 KB, stride 44 (gcd(11,32)=1)
    __shared__ float sLh[2][64];               // per-K-half l partials

    const int tid  = threadIdx.x;
    const int w    = tid >> 6;
    const int lane = tid & 63;
    const int h    = w & 1;          // K-half
    const int t    = w >> 1;         // token group (32 tokens)
    const int ln31 = lane & 31;
    const int hb   = lane >> 5;
    const int ln16 = lane & 15;      // O-phase / epilogue indices
    const int q4   = lane >> 4;
    const int m0   = blockIdx.x * 64;

    // Q fragments (B-operand, 32x32x16): token = m0 + t*32 + ln31,
    // cols (h*24 + i)*16 + hb*8 .. +8
    uint4 qf[24];
    {
        const unsigned short* qr = langb + (size_t)(m0 + t * 32 + ln31) * DIM
                                   + h * 384 + hb * 8;
        #pragma unroll
        for (int i = 0; i < 24; ++i)
            qf[i] = *(const uint4*)(qr + i * 16);
    }

    f32x4 accO[4][12];
    #pragma unroll
    for (int mt = 0; mt < 4; ++mt)
        #pragma unroll
        for (int dt = 0; dt < 12; ++dt)
            accO[mt][dt] = (f32x4){0.f, 0.f, 0.f, 0.f};
    float lpart = 0.f;

    // Prologue: DMA tile 0 into LDS
    #pragma unroll
    for (int i = 0; i < 12; ++i)
        async_cp16(latbS + ((size_t)i * 256 + tid) * 8,
                   sLat + (i * 256 + (tid & ~63)) * 8);
    __syncthreads();

    for (int s = 0; s < NSTEP; ++s) {
        // O-phase B frags for THIS step (global, coalesced, consumed after B2)
        uint4 bO[12];
        {
            const unsigned short* bt = latbT + (size_t)s * TILE_SH;
            #pragma unroll
            for (int dt = 0; dt < 12; ++dt)
                bO[dt] = *(const uint4*)(bt + (w * 192 + dt * 16 + ln16) * 32 + q4 * 8);
        }

        // ---- S-phase: one 32x32 tile over K-half h, two acc chains ----
        f32x16 De, Do;
        #pragma unroll
        for (int i2 = 0; i2 < 16; ++i2) { De[i2] = 0.f; Do[i2] = 0.f; }
        #pragma unroll
        for (int i = 0; i < 24; ++i) {
            bf16x8 a = *(const bf16x8*)&sLat[((h * 24 + i) * 64 + lane) * 8];
            bf16x8 b = *(const bf16x8*)&qf[i];
            if (i & 1) Do = __builtin_amdgcn_mfma_f32_32x32x16_bf16(a, b, Do, 0, 0, 0);
            else       De = __builtin_amdgcn_mfma_f32_32x32x16_bf16(a, b, De, 0, 0, 0);
        }
        f32x16 D = De + Do;

        // exchange writes: foreign half = partner's owned regs [(1-h)*8, +8)
        #pragma unroll
        for (int g2 = 0; g2 < 2; ++g2) {
            int rb = ((1 - h) * 2 + g2) * 4;
            sX[g2][w][lane] = make_float4(D[rb], D[rb + 1], D[rb + 2], D[rb + 3]);
        }
        __syncthreads();   // B1: S-reads of sLat done; sX published

        // DMA next tile (widest window: exch-read + exp + O-phase ahead)
        {
            int nt = (s + 1 < NSTEP) ? s + 1 : 0;
            const unsigned short* gs = latbS + (size_t)nt * TILE_SH;
            #pragma unroll
            for (int i = 0; i < 12; ++i)
                async_cp16(gs + (i * 256 + tid) * 8,
                           sLat + (i * 256 + (tid & ~63)) * 8);
        }

        // exchange reads + exp + sP write + l partial (owned regs [h*8, +8))
        #pragma unroll
        for (int g2 = 0; g2 < 2; ++g2) {
            float4 p = sX[g2][w ^ 1][lane];
            int rb = (h * 2 + g2) * 4;
            float v0 = D[rb]     + p.x;
            float v1 = D[rb + 1] + p.y;
            float v2 = D[rb + 2] + p.z;
            float v3 = D[rb + 3] + p.w;
            int row0 = (2 * h + g2) * 8 + 4 * hb;       // 4 consecutive lat rows
            int base = s * 32 + row0;
            float e0 = (base     < KLAT) ? __expf(v0) : 0.f;
            float e1 = (base + 1 < KLAT) ? __expf(v1) : 0.f;
            float e2 = (base + 2 < KLAT) ? __expf(v2) : 0.f;
            float e3 = (base + 3 < KLAT) ? __expf(v3) : 0.f;
            lpart += (e0 + e1) + (e2 + e3);
            uint2 pk;
            pk.x = (unsigned)f2bf(e0) | ((unsigned)f2bf(e1) << 16);
            pk.y = (unsigned)f2bf(e2) | ((unsigned)f2bf(e3) << 16);
            *(uint2*)&sP[(t * 32 + ln31) * 44 + row0] = pk;
        }
        __syncthreads();   // B2: sP published

        // ---- O-phase: O[tok][d] += P[tok][lat] * Lat[lat][d] ----
        bf16x8 pA[4];
        #pragma unroll
        for (int mt = 0; mt < 4; ++mt)
            pA[mt] = *(const bf16x8*)&sP[(mt * 16 + ln16) * 44 + q4 * 8];
        #pragma unroll
        for (int dt = 0; dt < 12; ++dt) {
            bf16x8 b = *(const bf16x8*)&bO[dt];
            #pragma unroll
            for (int mt = 0; mt < 4; ++mt)
                accO[mt][dt] = __builtin_amdgcn_mfma_f32_16x16x32_bf16(
                    pA[mt], b, accO[mt][dt], 0, 0, 0);
        }
        __syncthreads();   // B3: drains DMA (tile s+1 ready); sP reads done
    }

    // l: sum lane halves (same token), then combine the two K-half waves
    lpart += __shfl_xor(lpart, 32, 64);
    if (lane < 32) sLh[h][t * 32 + lane] = lpart;
    __syncthreads();

    // epilogue: /l + lang + special-token override, fp32 out
    #pragma unroll
    for (int mt = 0; mt < 4; ++mt) {
        int tl0 = mt * 16 + q4 * 4;
        float linv[4]; int fid[4];
        #pragma unroll
        for (int r = 0; r < 4; ++r) {
            linv[r] = 1.0f / (sLh[0][tl0 + r] + sLh[1][tl0 + r]);
            fid[r]  = x[(m0 + tl0 + r) * 8];
        }
        #pragma unroll
        for (int dt = 0; dt < 12; ++dt) {
            int d = w * 192 + dt * 16 + ln16;
            #pragma unroll
            for (int r = 0; r < 4; ++r) {
                int tok = m0 + tl0 + r;
                float v = accO[mt][dt][r] * linv[r] + bf2f(langb[(size_t)tok * DIM + d]);
                if (fid[r] < 4) v = cemb[(size_t)fid[r] * DIM + d];  // PAD/CLS/SEP/UNK
                out[(size_t)tok * DIM + d] = v;
            }
        }
    }
}

// ---------------------------------------------------------------------------
extern "C" void kernel_launch(void* const* d_in, const int* in_sizes, int n_in,
                              void* d_out, int out_size, void* d_ws, size_t ws_size,
                              hipStream_t stream) {
    const int*   x      = (const int*)d_in[0];     // (16,1024,8) int
    const float* cemb   = (const float*)d_in[1];   // (30000,768) f32
    const float* latent = (const float*)d_in[2];   // (5000,768) f32
    float* out = (float*)d_out;                    // (16,1024,768) f32

    unsigned short* langb = (unsigned short*)d_ws;                          // 25.2 MB
    unsigned short* latbS = langb + (size_t)NTOK * DIM;                     // 7.7 MB
    unsigned short* latbT = latbS + (size_t)NSTEP * TILE_SH;                // 7.7 MB

    int nG = NSTEP * 48 * 64;            // 8-short groups in each latent buffer
    cvt_lat<<<(nG + 255) / 256, 256, 0, stream>>>(latent, latbS, latbT);
    build_lang<<<NTOK, 192, 0, stream>>>(x, cemb, langb);
    fused_sde<<<NTOK / 64, 256, 0, stream>>>(x, cemb, langb, latbS, latbT, out);
}

// Round 4
// 610.364 us; speedup vs baseline: 1.1385x; 1.1385x over previous
//
#include <hip/hip_runtime.h>

// Problem constants
#define PAD_ID 0
#define NTOK   16384          // B*L = 16*1024
#define DIM    768
#define KLAT   5000
#define KPAD   5024           // 157*32, zero-padded latent rows
#define NSTEP  157            // 5024/32
#define TILE_SH 24576         // shorts per 32x768 tile (48 KB)

typedef float f32x4  __attribute__((ext_vector_type(4)));
typedef __bf16 bf16x8 __attribute__((ext_vector_type(8)));

__device__ __forceinline__ unsigned short f2bf(float f) {
    unsigned int u = __float_as_uint(f);
    u += 0x7fffu + ((u >> 16) & 1u);   // RNE
    return (unsigned short)(u >> 16);
}
__device__ __forceinline__ float bf2f(unsigned short h) {
    return __uint_as_float(((unsigned int)h) << 16);
}
__device__ __forceinline__ float fast_tanh(float x) {
    return 1.0f - 2.0f / (__expf(2.0f * x) + 1.0f);
}
__device__ __forceinline__ void async_cp16(const unsigned short* g, unsigned short* l) {
    __builtin_amdgcn_global_load_lds(
        (const __attribute__((address_space(1))) unsigned int*)g,
        (__attribute__((address_space(3))) unsigned int*)l, 16, 0, 0);
}

// ---------------------------------------------------------------------------
// Kernel 0: latent -> latbS (16x16x32 A-frag order, round-2 layout) and
//           latbT (d-major), bf16.
//   latbS[t][kf][half][lane][j] = Lat[t*32 + half*16 + (lane&15)]
//                                    [kf*32 + (lane>>4)*8 + j]
//   latbT[t][d][kk]             = Lat[t*32 + kk][d]
// ---------------------------------------------------------------------------
__global__ __launch_bounds__(256) void cvt_lat(const float* __restrict__ latent,
                                               unsigned short* __restrict__ latbS,
                                               unsigned short* __restrict__ latbT) {
    int g = blockIdx.x * 256 + threadIdx.x;
    if (g >= NSTEP * 48 * 64) return;
    // ---- S part (A-frag order for 16x16x32) ----
    {
        int lane = g & 63; int rest = g >> 6;
        int half = rest & 1; int kfr = rest >> 1;
        int kf = kfr % 24;  int t = kfr / 24;
        int row = t * 32 + half * 16 + (lane & 15);
        int col = kf * 32 + (lane >> 4) * 8;
        float4 v0 = make_float4(0.f,0.f,0.f,0.f), v1 = v0;
        if (row < KLAT) {
            v0 = *(const float4*)(latent + (long)row * DIM + col);
            v1 = *(const float4*)(latent + (long)row * DIM + col + 4);
        }
        uint4 o;
        o.x = (unsigned)f2bf(v0.x) | ((unsigned)f2bf(v0.y) << 16);
        o.y = (unsigned)f2bf(v0.z) | ((unsigned)f2bf(v0.w) << 16);
        o.z = (unsigned)f2bf(v1.x) | ((unsigned)f2bf(v1.y) << 16);
        o.w = (unsigned)f2bf(v1.z) | ((unsigned)f2bf(v1.w) << 16);
        *(uint4*)(latbS + (size_t)g * 8) = o;
    }
    // ---- T part (d-major) ----
    {
        int kk8 = g & 3; int rest = g >> 2;
        int d = rest % DIM; int t = rest / DIM;
        unsigned short v[8];
        #pragma unroll
        for (int j = 0; j < 8; ++j) {
            int row = t * 32 + kk8 * 8 + j;
            v[j] = (row < KLAT) ? f2bf(latent[(long)row * DIM + d]) : (unsigned short)0;
        }
        *(uint4*)(latbT + (size_t)g * 8) = *(uint4*)v;
    }
}

// ---------------------------------------------------------------------------
// Kernel 1: lang_emb = tanh(masked-mean of char embeddings), stored bf16.
// ---------------------------------------------------------------------------
__global__ __launch_bounds__(192) void build_lang(const int* __restrict__ x,
                                                  const float* __restrict__ cemb,
                                                  unsigned short* __restrict__ langb) {
    int tok = blockIdx.x;
    int t = threadIdx.x;
    const int* xs = x + tok * 8;
    int ids[8]; int cnt = 0;
    #pragma unroll
    for (int c = 0; c < 8; ++c) { ids[c] = xs[c]; cnt += (ids[c] != PAD_ID); }
    float4 acc = make_float4(0.f, 0.f, 0.f, 0.f);
    #pragma unroll
    for (int c = 0; c < 8; ++c) {
        if (ids[c] != PAD_ID) {
            float4 v = *(const float4*)(cemb + (long)ids[c] * DIM + t * 4);
            acc.x += v.x; acc.y += v.y; acc.z += v.z; acc.w += v.w;
        }
    }
    float rc = 1.0f / (float)max(cnt, 1);
    unsigned int u0 = (unsigned int)f2bf(fast_tanh(acc.x * rc)) |
                      ((unsigned int)f2bf(fast_tanh(acc.y * rc)) << 16);
    unsigned int u1 = (unsigned int)f2bf(fast_tanh(acc.z * rc)) |
                      ((unsigned int)f2bf(fast_tanh(acc.w * rc)) << 16);
    *(uint2*)(langb + tok * DIM + t * 4) = make_uint2(u0, u1);
}

// ---------------------------------------------------------------------------
// Kernel 2: fused S^T -> exp -> P@Lat -> /l + lang + special override.
// 256 blocks x 64 tokens, 512 threads (8 waves -> 2 waves/SIMD).
// Wave w = (tg = w>>1 : 16-token group, h = w&1 : 16-latent half):
//   S-phase: 16-tok x 16-lat subtile, FULL K=768 (no exchange):
//     24 ds_read_b128 A-frags + 24 mfma_16x16x32, Q frags (96 VGPR) in regs.
//   exp -> sP (64x32 P, stride-44 rows); l partial per (tg,h) wave.
//   O-phase: wave owns d-slice 96: accO[4][6] (96 regs), bO from latbT global.
// sLat double-buffered (2x48 KB): DMA for s+1 issues at TOP of step s,
// drains at end-of-step barrier (full-step window). 2 barriers/step.
// ---------------------------------------------------------------------------
__global__ __launch_bounds__(512, 2) void fused_sde(
        const int* __restrict__ x, const float* __restrict__ cemb,
        const unsigned short* __restrict__ langb,
        const unsigned short* __restrict__ latbS,
        const unsigned short* __restrict__ latbT,
        float* __restrict__ out) {
    __shared__ unsigned short sLat[2][TILE_SH]; // 96 KB double-buffered tile
    __shared__ unsigned short sP[64 * 44];      // 5.5 KB, stride 44
    __shared__ float sLh[8][16];                // per-wave l partials

    const int tid  = threadIdx.x;
    const int w    = tid >> 6;
    const int lane = tid & 63;
    const int tg   = w >> 1;         // token group (16 tokens)
    const int h    = w & 1;          // latent half (16 of 32)
    const int ln16 = lane & 15;
    const int q4   = lane >> 4;
    const int m0   = blockIdx.x * 64;

    // Q fragments (B-operand): token = m0 + tg*16 + ln16, full K
    uint4 qf[24];
    {
        const unsigned short* qr = langb + (size_t)(m0 + tg * 16 + ln16) * DIM + q4 * 8;
        #pragma unroll
        for (int kf = 0; kf < 24; ++kf)
            qf[kf] = *(const uint4*)(qr + kf * 32);
    }

    f32x4 accO[4][6];
    #pragma unroll
    for (int mt = 0; mt < 4; ++mt)
        #pragma unroll
        for (int dt = 0; dt < 6; ++dt)
            accO[mt][dt] = (f32x4){0.f, 0.f, 0.f, 0.f};
    float lpart = 0.f;

    // Prologue: DMA tile 0 into buf 0
    #pragma unroll
    for (int i = 0; i < 6; ++i)
        async_cp16(latbS + ((size_t)i * 512 + tid) * 8,
                   &sLat[0][(i * 512 + (tid & ~63)) * 8]);
    __syncthreads();

    for (int s = 0; s < NSTEP; ++s) {
        const int cur = s & 1;
        // DMA next tile into the other buffer (drains at end-of-step barrier)
        {
            int nt = (s + 1 < NSTEP) ? s + 1 : 0;
            const unsigned short* gs = latbS + (size_t)nt * TILE_SH;
            #pragma unroll
            for (int i = 0; i < 6; ++i)
                async_cp16(gs + (i * 512 + tid) * 8,
                           &sLat[1 - cur][(i * 512 + (tid & ~63)) * 8]);
        }
        // O-phase B frags for this step (global, coalesced; consumed after B1)
        uint4 bO[6];
        {
            const unsigned short* bt = latbT + (size_t)s * TILE_SH;
            #pragma unroll
            for (int dt = 0; dt < 6; ++dt)
                bO[dt] = *(const uint4*)(bt + (w * 96 + dt * 16 + ln16) * 32 + q4 * 8);
        }

        // ---- S-phase: 16-tok x 16-lat subtile, full K, two short chains ----
        f32x4 se = {0.f,0.f,0.f,0.f}, so = {0.f,0.f,0.f,0.f};
        #pragma unroll
        for (int kf = 0; kf < 24; ++kf) {
            bf16x8 a = *(const bf16x8*)&sLat[cur][(kf * 128 + h * 64 + lane) * 8];
            bf16x8 b = *(const bf16x8*)&qf[kf];
            if (kf & 1) so = __builtin_amdgcn_mfma_f32_16x16x32_bf16(a, b, so, 0, 0, 0);
            else        se = __builtin_amdgcn_mfma_f32_16x16x32_bf16(a, b, se, 0, 0, 0);
        }
        f32x4 sv = se + so;

        // ---- exp + sP write + l partial (lane's token col = tg*16+ln16) ----
        {
            int lat0 = s * 32 + h * 16 + q4 * 4;
            float e0 = (lat0     < KLAT) ? __expf(sv[0]) : 0.f;
            float e1 = (lat0 + 1 < KLAT) ? __expf(sv[1]) : 0.f;
            float e2 = (lat0 + 2 < KLAT) ? __expf(sv[2]) : 0.f;
            float e3 = (lat0 + 3 < KLAT) ? __expf(sv[3]) : 0.f;
            lpart += (e0 + e1) + (e2 + e3);
            uint2 pk;
            pk.x = (unsigned)f2bf(e0) | ((unsigned)f2bf(e1) << 16);
            pk.y = (unsigned)f2bf(e2) | ((unsigned)f2bf(e3) << 16);
            *(uint2*)&sP[(tg * 16 + ln16) * 44 + h * 16 + q4 * 4] = pk;
        }
        __syncthreads();   // B1: S-reads of sLat[cur] done; sP published

        // ---- O-phase: O[tok][d] += P[tok][lat] * Lat[lat][d] ----
        #pragma unroll
        for (int mt = 0; mt < 4; ++mt) {
            bf16x8 pA = *(const bf16x8*)&sP[(mt * 16 + ln16) * 44 + q4 * 8];
            #pragma unroll
            for (int dt = 0; dt < 6; ++dt) {
                bf16x8 b = *(const bf16x8*)&bO[dt];
                accO[mt][dt] = __builtin_amdgcn_mfma_f32_16x16x32_bf16(
                    pA, b, accO[mt][dt], 0, 0, 0);
            }
        }
        __syncthreads();   // B2: DMA (next tile) drained; sP reads done
    }

    // l partials: sum quads (token preserved under xor 16/32), publish per wave
    lpart += __shfl_xor(lpart, 16, 64);
    lpart += __shfl_xor(lpart, 32, 64);
    if (lane < 16) sLh[w][lane] = lpart;
    __syncthreads();

    // epilogue: /l + lang + special-token override, fp32 out (d-slice w*96)
    #pragma unroll
    for (int mt = 0; mt < 4; ++mt) {
        int tl0 = mt * 16 + q4 * 4;
        float linv[4]; int fid[4];
        #pragma unroll
        for (int r = 0; r < 4; ++r) {
            linv[r] = 1.0f / (sLh[mt * 2][q4 * 4 + r] + sLh[mt * 2 + 1][q4 * 4 + r]);
            fid[r]  = x[(m0 + tl0 + r) * 8];
        }
        #pragma unroll
        for (int dt = 0; dt < 6; ++dt) {
            int d = w * 96 + dt * 16 + ln16;
            #pragma unroll
            for (int r = 0; r < 4; ++r) {
                int tok = m0 + tl0 + r;
                float v = accO[mt][dt][r] * linv[r] + bf2f(langb[(size_t)tok * DIM + d]);
                if (fid[r] < 4) v = cemb[(size_t)fid[r] * DIM + d];  // PAD/CLS/SEP/UNK
                out[(size_t)tok * DIM + d] = v;
            }
        }
    }
}

// ---------------------------------------------------------------------------
extern "C" void kernel_launch(void* const* d_in, const int* in_sizes, int n_in,
                              void* d_out, int out_size, void* d_ws, size_t ws_size,
                              hipStream_t stream) {
    const int*   x      = (const int*)d_in[0];     // (16,1024,8) int
    const float* cemb   = (const float*)d_in[1];   // (30000,768) f32
    const float* latent = (const float*)d_in[2];   // (5000,768) f32
    float* out = (float*)d_out;                    // (16,1024,768) f32

    unsigned short* langb = (unsigned short*)d_ws;                          // 25.2 MB
    unsigned short* latbS = langb + (size_t)NTOK * DIM;                     // 7.7 MB
    unsigned short* latbT = latbS + (size_t)NSTEP * TILE_SH;                // 7.7 MB

    int nG = NSTEP * 48 * 64;            // 8-short groups in each latent buffer
    cvt_lat<<<(nG + 255) / 256, 256, 0, stream>>>(latent, latbS, latbT);
    build_lang<<<NTOK, 192, 0, stream>>>(x, cemb, langb);
    fused_sde<<<NTOK / 64, 512, 0, stream>>>(x, cemb, langb, latbS, latbT, out);
}